// Round 16
// baseline (93.965 us; speedup 1.0000x reference)
//
#include <hip/hip_runtime.h>
#include <hip/hip_fp16.h>

#define NN 16384
#define DD 256
#define CAP 160        // per-row list capacity, mult of 32 (deg ~ Poisson(64), max ~112)
#define NB 128         // sorter blocks
#define BK 64
#define LDAP 72        // padded LDS row stride in bf16 elems (144 B)
#define PLP 2099200    // xab plane stride in f16 elems: (16384+16)*128 (16 zero pad rows)
#define XUP 2097152    // xu plane stride in f16 elems: 16384*128

typedef __attribute__((ext_vector_type(8))) __bf16 bf16x8;
typedef __attribute__((ext_vector_type(8))) unsigned short u16x8;
typedef __attribute__((ext_vector_type(4))) float f32x4;

__device__ __forceinline__ unsigned short f2bn(float f) {
    __bf16 h = (__bf16)f;
    return __builtin_bit_cast(unsigned short, h);
}

// ---- K1 prep: 0..127 coarse hist | 128..191 x->bf16 | 192..199 W->bf16 | 200 pad --
__global__ __launch_bounds__(512) void k_prep(const int* __restrict__ ei,
                                              unsigned int* __restrict__ Hc,
                                              const float* __restrict__ x,
                                              const float* __restrict__ Wu,
                                              const float* __restrict__ Wa,
                                              unsigned short* __restrict__ xb,
                                              unsigned short* __restrict__ wb,
                                              __half* __restrict__ xab,
                                              int E, int epb) {
    const int b = blockIdx.x;
    const int t = threadIdx.x;

    if (b >= 128) {
        if (b < 192) {
            const int w = b - 128;
#pragma unroll
            for (int i = 0; i < 32; ++i) {
                const int f4 = w * 16384 + i * 512 + t;
                float4 v = *(const float4*)(x + (size_t)f4 * 4);
                ushort4 o;
                o.x = f2bn(v.x); o.y = f2bn(v.y); o.z = f2bn(v.z); o.w = f2bn(v.w);
                *(ushort4*)(xb + (size_t)f4 * 4) = o;
            }
        } else if (b < 200) {
            const int w = b - 192;
            const float* src = (w < 4) ? Wu : Wa;
            unsigned short* dst = wb + ((w < 4) ? 0 : 65536);
            const int c0 = (w & 3) * 4096;
#pragma unroll
            for (int i = 0; i < 8; ++i) {
                const int f4 = c0 + i * 512 + t;
                float4 v = *(const float4*)(src + (size_t)f4 * 4);
                ushort4 o;
                o.x = f2bn(v.x); o.y = f2bn(v.y); o.z = f2bn(v.z); o.w = f2bn(v.w);
                *(ushort4*)(dst + (size_t)f4 * 4) = o;
            }
        } else {
            // zero the 16 pad rows of each xab plane (sentinel target)
            uint4 z; z.x = 0u; z.y = 0u; z.z = 0u; z.w = 0u;
            ((uint4*)xab)[(size_t)(t >> 8) * (PLP / 8) + (NN * 128 / 8) + (t & 255)] = z;
        }
        return;
    }

    __shared__ unsigned int hc[128];
    if (t < 128) hc[t] = 0u;
    __syncthreads();

    const int e0 = b * epb;
    const int e1 = min(e0 + epb, E);
    for (int e = e0 + t; e < e1; e += 512) {
        const int s = ei[e];
        const int d = ei[E + e];
        atomicAdd(&hc[s >> 7], 1u);
        atomicAdd(&hc[d >> 7], 1u);
    }
    __syncthreads();
    if (t < 128) Hc[b * 128 + t] = hc[t];
}

// ---- K2 scan1 (1 block): runOfs[b][k] = bstart[k] + prefix_b(Hc[.][k]) ------------
__global__ __launch_bounds__(512) void k_scan1(const unsigned int* __restrict__ Hc,
                                               unsigned int* __restrict__ runOfs,
                                               unsigned int* __restrict__ bstart) {
    __shared__ unsigned short h16[128 * 128];
    __shared__ unsigned int tot[128];
    __shared__ unsigned int bs[129];
    const int t = threadIdx.x;

    for (int i = t; i < 128 * 128; i += 512) h16[i] = (unsigned short)Hc[i];
    __syncthreads();

    if (t < 128) {
        unsigned int s = 0;
#pragma unroll 8
        for (int b = 0; b < 128; ++b) {
            const unsigned int v = h16[b * 128 + t];
            h16[b * 128 + t] = (unsigned short)s;
            s += v;
        }
        tot[t] = s;
    }
    __syncthreads();
    if (t == 0) {
        unsigned int s = 0;
        for (int k = 0; k < 128; ++k) { bs[k] = s; s += tot[k]; }
        bs[128] = s;
    }
    __syncthreads();

    for (int i = t; i < 128 * 128; i += 512)
        runOfs[i] = bs[i & 127] + (unsigned int)h16[i];
    if (t < 129) bstart[t] = bs[t];
}

// ---- K3: blocks 0..511 GEMM (128x128, XCD-swizzled); 512..639 bucket-scatter ------
// colq 0,1: xu[plane colq]  = f16(x@Wu^T + bu + ba)
// colq 2,3: xab[plane colq-2] = f16(x@Wa^T)
__global__ __launch_bounds__(512) void k_gemm_fill1(const unsigned short* __restrict__ xb,
                                                    const unsigned short* __restrict__ wb,
                                                    const float* __restrict__ bu,
                                                    const float* __restrict__ ba,
                                                    const int* __restrict__ ei,
                                                    const unsigned int* __restrict__ runOfs,
                                                    unsigned int* __restrict__ edgebuf,
                                                    __half* __restrict__ xu,
                                                    __half* __restrict__ xab,
                                                    int E, int epb) {
    __shared__ __align__(16) unsigned short smem[2 * 128 * LDAP];  // 36864 B
    const int t = threadIdx.x;

    if (blockIdx.x >= 512) {
        // ---- fill1: append (row<<14)|nbr to coarse-bucket runs (dense writes) ----
        unsigned int* cur = (unsigned int*)smem;
        const int b = blockIdx.x - 512;
        if (t < 128) cur[t] = runOfs[b * 128 + t];
        __syncthreads();
        const int e0 = b * epb;
        const int e1 = min(e0 + epb, E);
        for (int e = e0 + t; e < e1; e += 512) {
            const unsigned int s = (unsigned int)ei[e];
            const unsigned int d = (unsigned int)ei[E + e];
            const unsigned int p1 = atomicAdd(&cur[s >> 7], 1u);
            edgebuf[p1] = (s << 14) | d;
            const unsigned int p2 = atomicAdd(&cur[d >> 7], 1u);
            edgebuf[p2] = (d << 14) | s;
        }
        return;
    }

    unsigned short* As = smem;
    unsigned short* Bs = smem + 128 * LDAP;

    const int lane = t & 63;
    const int wid = t >> 6;
    const int wr = wid >> 2;
    const int wc = wid & 3;
    const int rowp = blockIdx.x & 127;   // XCD swizzle: 4 colq blocks 128 apart -> same XCD
    const int colq = blockIdx.x >> 7;
    const int row0 = rowp << 7;
    const unsigned short* Wsrc = wb + ((size_t)colq << 15);

    f32x4 acc[4][2] = {};

    for (int k0 = 0; k0 < DD; k0 += BK) {
        uint4 ra_[2], rb_[2];
#pragma unroll
        for (int i = 0; i < 2; ++i) {
            const int f = i * 512 + t;
            const int r = f >> 3, s = f & 7;
            ra_[i] = *(const uint4*)(xb + (size_t)(row0 + r) * DD + k0 + s * 8);
            rb_[i] = *(const uint4*)(Wsrc + (size_t)r * DD + k0 + s * 8);
        }
        __syncthreads();
#pragma unroll
        for (int i = 0; i < 2; ++i) {
            const int f = i * 512 + t;
            const int r = f >> 3, s = f & 7;
            *(uint4*)(&As[r * LDAP + s * 8]) = ra_[i];
            *(uint4*)(&Bs[r * LDAP + s * 8]) = rb_[i];
        }
        __syncthreads();
#pragma unroll
        for (int kk = 0; kk < 2; ++kk) {
            bf16x8 av[4], bv[2];
#pragma unroll
            for (int f = 0; f < 4; ++f) {
                uint4 ra = *(const uint4*)(&As[(wr * 64 + f * 16 + (lane & 15)) * LDAP + kk * 32 + (lane >> 4) * 8]);
                av[f] = __builtin_bit_cast(bf16x8, ra);
            }
#pragma unroll
            for (int f = 0; f < 2; ++f) {
                uint4 rv = *(const uint4*)(&Bs[(wc * 32 + f * 16 + (lane & 15)) * LDAP + kk * 32 + (lane >> 4) * 8]);
                bv[f] = __builtin_bit_cast(bf16x8, rv);
            }
#pragma unroll
            for (int fm = 0; fm < 4; ++fm)
#pragma unroll
                for (int fn = 0; fn < 2; ++fn)
                    acc[fm][fn] = __builtin_amdgcn_mfma_f32_16x16x32_bf16(
                        av[fm], bv[fn], acc[fm][fn], 0, 0, 0);
        }
    }

    const int gr0 = row0 + wr * 64 + ((lane >> 4) << 2);
    const int lc0 = wc * 32 + (lane & 15);
    if (colq < 2) {
        __half* up = xu + (size_t)colq * XUP;
#pragma unroll
        for (int fn = 0; fn < 2; ++fn) {
            const int c = lc0 + fn * 16;
            const float bias = bu[(colq << 7) + c] + ba[(colq << 7) + c];
#pragma unroll
            for (int fm = 0; fm < 4; ++fm) {
                const int r = gr0 + fm * 16;
#pragma unroll
                for (int i = 0; i < 4; ++i)
                    up[(size_t)(r + i) * 128 + c] = __float2half(acc[fm][fn][i] + bias);
            }
        }
    } else {
        __half* xp = xab + (size_t)(colq - 2) * PLP;
#pragma unroll
        for (int fn = 0; fn < 2; ++fn) {
            const int c = lc0 + fn * 16;
#pragma unroll
            for (int fm = 0; fm < 4; ++fm) {
                const int r = gr0 + fm * 16;
#pragma unroll
                for (int i = 0; i < 4; ++i)
                    xp[(size_t)(r + i) * 128 + c] = __float2half(acc[fm][fn][i]);
            }
        }
    }
}

// ---- K4 fill2: build lists in LDS, DEDUP IN PLACE (per-wave bitmap), --------------
//      sentinel-pad to x32, write coalesced. Gather then needs no dedup at all.
__global__ __launch_bounds__(512) void k_fill2(const unsigned int* __restrict__ edgebuf,
                                               const unsigned int* __restrict__ bstart,
                                               unsigned short* __restrict__ list,
                                               unsigned int* __restrict__ cnt) {
    __shared__ unsigned short ll[128 * CAP];  // 40960 B
    __shared__ unsigned int dbm[8][512];      // 16384 B: per-wave dedup bitmap
    __shared__ unsigned int cur[128];
    const int k = blockIdx.x;
    const int t = threadIdx.x;
    const int w = t >> 6;
    const int lane = t & 63;

    if (t < 128) cur[t] = 0u;
    {
        u16x8 s8;
#pragma unroll
        for (int j = 0; j < 8; ++j) s8[j] = (unsigned short)NN;   // sentinel
        for (int i = t; i < 128 * CAP / 8; i += 512) *(u16x8*)(ll + i * 8) = s8;
    }
    __syncthreads();

    const unsigned int s0 = bstart[k], s1 = bstart[k + 1];
    for (unsigned int j = s0 + t; j < s1; j += 512) {
        const unsigned int e = edgebuf[j];
        const int lr = (int)((e >> 14) & 127u);
        const unsigned short nbr = (unsigned short)(e & 16383u);
        const unsigned int p = atomicAdd(&cur[lr], 1u);
        if (p < CAP) ll[lr * CAP + p] = nbr;
    }
    __syncthreads();

    // dedup: wave w owns rows w*16 .. w*16+15; 2 KiB bitmap reused per row.
    uint4 z4; z4.x = 0u; z4.y = 0u; z4.z = 0u; z4.w = 0u;
    for (int rr = 0; rr < 16; ++rr) {
        const int lr = (w << 4) + rr;
        ((uint4*)&dbm[w][0])[lane] = z4;
        ((uint4*)&dbm[w][0])[64 + lane] = z4;
        const int m = min((int)cur[lr], CAP);
        for (int i = lane; i < m; i += 64) {
            const int idx = ll[lr * CAP + i];
            const unsigned int bit = 1u << (idx & 31);
            const unsigned int old = atomicOr(&dbm[w][idx >> 5], bit);
            if (old & bit) ll[lr * CAP + i] = (unsigned short)NN;  // duplicate
        }
    }
    __syncthreads();

    // 4 threads per row write that row's stripes up to padded count.
    const int lr = t >> 2;
    const int sub = t & 3;
    const unsigned int padded = min((cur[lr] + 31u) & ~31u, (unsigned int)CAP);
    if (sub == 0) cnt[(k << 7) + lr] = padded;
    unsigned short* lrow = list + (size_t)((k << 7) + lr) * CAP;
    for (unsigned int q = sub; q * 8 < padded; q += 4)
        *(u16x8*)(lrow + q * 8) = *(const u16x8*)(ll + lr * CAP + q * 8);
}

// ---- K5: gather, both planes in one dispatch (grid 8192, plane = blk>>12) ---------
// 1 wave per row, 4 rows/block. Lists are pre-deduped + sentinel-padded -> pure
// streaming: no LDS, no atomics, no staging. List octets read from global
// (16-lane broadcast, L2-hot). Epilogue: out = xu_plane[row] + acc (pure store).
#define ACC4(S, V) { \
    acc[S][0] = __hadd2(acc[S][0], __builtin_bit_cast(__half2, (V).x)); \
    acc[S][1] = __hadd2(acc[S][1], __builtin_bit_cast(__half2, (V).y)); \
    acc[S][2] = __hadd2(acc[S][2], __builtin_bit_cast(__half2, (V).z)); \
    acc[S][3] = __hadd2(acc[S][3], __builtin_bit_cast(__half2, (V).w)); }

__global__ __launch_bounds__(256) void k_gather(const unsigned int* __restrict__ cnt,
                                                const unsigned short* __restrict__ list,
                                                const __half* __restrict__ xab,
                                                const __half* __restrict__ xu,
                                                float* __restrict__ out) {
    const int t = threadIdx.x;
    const int wid = t >> 6;
    const int lane = t & 63;
    const int pb = blockIdx.x >> 12;               // plane 0/1
    const int row = ((blockIdx.x & 4095) << 2) + wid;
    const __half* plane = xab + (size_t)pb * PLP;
    const __half* uplane = xu + (size_t)pb * XUP;

    const int m = (int)cnt[row];                   // multiple of 32
    const unsigned short* gl = list + (size_t)row * CAP;

    const int lg = lane >> 4;      // neighbor-octet slot 0..3
    const int li = lane & 15;      // dim group: f16 dims li*8..li*8+7
    __half2 acc[4][4];
    const __half2 z2 = __float2half2_rn(0.0f);
#pragma unroll
    for (int s = 0; s < 4; ++s) { acc[s][0] = z2; acc[s][1] = z2; acc[s][2] = z2; acc[s][3] = z2; }

    for (int i = 0; i < m; i += 32) {
        const u16x8 e = *(const u16x8*)(gl + i + lg * 8);  // 16B broadcast per 16 lanes
        uint4 v[8];
#pragma unroll
        for (int j = 0; j < 8; ++j)
            v[j] = *(const uint4*)(plane + ((size_t)e[j] << 7) + li * 8);
#pragma unroll
        for (int j = 0; j < 8; ++j) ACC4(j & 3, v[j]);
    }

#pragma unroll
    for (int k = 0; k < 4; ++k) {
        acc[0][k] = __hadd2(acc[0][k], __hadd2(acc[1][k], __hadd2(acc[2][k], acc[3][k])));
        int v = __builtin_bit_cast(int, acc[0][k]);
        v = __shfl_xor(v, 16, 64);
        acc[0][k] = __hadd2(acc[0][k], __builtin_bit_cast(__half2, v));
        v = __builtin_bit_cast(int, acc[0][k]);
        v = __shfl_xor(v, 32, 64);
        acc[0][k] = __hadd2(acc[0][k], __builtin_bit_cast(__half2, v));
    }

    if (lg == 0) {
        const uint4 u = *(const uint4*)(uplane + (size_t)row * 128 + li * 8);
        float4 o0, o1;
        float2 f, g;
        f = __half22float2(acc[0][0]); g = __half22float2(__builtin_bit_cast(__half2, u.x));
        o0.x = f.x + g.x; o0.y = f.y + g.y;
        f = __half22float2(acc[0][1]); g = __half22float2(__builtin_bit_cast(__half2, u.y));
        o0.z = f.x + g.x; o0.w = f.y + g.y;
        f = __half22float2(acc[0][2]); g = __half22float2(__builtin_bit_cast(__half2, u.z));
        o1.x = f.x + g.x; o1.y = f.y + g.y;
        f = __half22float2(acc[0][3]); g = __half22float2(__builtin_bit_cast(__half2, u.w));
        o1.z = f.x + g.x; o1.w = f.y + g.y;
        float4* po = (float4*)(out + (size_t)row * DD + (pb << 7) + li * 8);
        po[0] = o0; po[1] = o1;
    }
}

extern "C" void kernel_launch(void* const* d_in, const int* in_sizes, int n_in,
                              void* d_out, int out_size, void* d_ws, size_t ws_size,
                              hipStream_t stream) {
    const float* x  = (const float*)d_in[0];
    const int*   ei = (const int*)d_in[1];
    const float* Wu = (const float*)d_in[2];
    const float* bu = (const float*)d_in[3];
    const float* Wa = (const float*)d_in[4];
    const float* ba = (const float*)d_in[5];
    float* out = (float*)d_out;

    const int E = in_sizes[1] / 2;
    const int epb = (E + NB - 1) / NB;

    char* ws = (char*)d_ws;
    __half* xab = (__half*)ws;                                // 0:        8,396,800 B (2 planes + pads)
    __half* xu = (__half*)(ws + 8396800);                     // 8,388,608 B (2 planes)
    unsigned short* wb = (unsigned short*)(ws + 16785408);    // 262,144 B bf16 [Wu;Wa]
    unsigned short* xb = (unsigned short*)(ws + 17047552);    // 8,388,608 B bf16 x
    unsigned int* Hc = (unsigned int*)(ws + 25436160);        // 65,536 B
    unsigned int* runOfs = (unsigned int*)(ws + 25501696);    // 65,536 B
    unsigned int* bstart = (unsigned int*)(ws + 25567232);    // 1,024 B
    unsigned int* edgebuf = (unsigned int*)(ws + 25568256);   // 4,194,304 B
    unsigned int* cnt = (unsigned int*)(ws + 29762560);       // 65,536 B
    unsigned short* list = (unsigned short*)(ws + 29828096);  // 5,242,880 B (CAP=160)

    k_prep<<<201, 512, 0, stream>>>(ei, Hc, x, Wu, Wa, xb, wb, xab, E, epb);
    k_scan1<<<1, 512, 0, stream>>>(Hc, runOfs, bstart);
    k_gemm_fill1<<<640, 512, 0, stream>>>(xb, wb, bu, ba, ei, runOfs, edgebuf, xu, xab, E, epb);
    k_fill2<<<NB, 512, 0, stream>>>(edgebuf, bstart, list, cnt);
    k_gather<<<2 * (NN / 4), 256, 0, stream>>>(cnt, list, xab, xu, out);
}